// Round 11
// baseline (165.873 us; speedup 1.0000x reference)
//
#include <hip/hip_runtime.h>
#include <math.h>

// Focal_loss2 — single fused dispatch. R11 = R10 (z-paired rolling y-march,
// XCD swizzle) + (1) wave-level plane SHARING: partner lanes (lane^PSH, same
// xq, adjacent z-pair) each load 3 of the 6 planes their pair-of-pairs needs
// and exchange one row via __shfl (DS pipe idle; 4->3 logit requests/step);
// (2) PREDICATED gt loads: gt only read when the quad contains a 3x3x3 local
// max (~25-29% of quads; correct since contribution needs max AND gt==-1).
// Model (confirmed R4/R7/R10): duration ~ L1-missing VMEM requests at a fixed
// per-CU service rate; requests/step 6 -> ~3.6.
//   neg: w = sigmoid(x)^2 * (gt==-1) * (x is 3x3x3 local max); loss += softplus(x)*w
//        local-max test in logit space (monotone sigmoid; validated R3-R10, absmax 0.0)
//   pos: 64 coords/batch/level gather; w1=(1-sigmoid)^2; per-(b,tag) min of w1
// ws (floats): [0]=lossneg_a [1]=wneg_a [2]=lossneg_b [3]=wneg_b
//              [4]=losspos_a [5]=cntpos_a [6]=losspos_b [7]=cntpos_b [8]=block counter
// out: [0]=cls_loss_pos [1]=cls_loss_neg [2]=count_pos [3]=count_neg
//      [4]=wsum_pos [5]=wsum_neg [6..37]=pred_prob_min[2][B=2][T=8]

#define NBLK_A 512    // 4 vol x 8 z-groups(16 z) x 16 y-chunks(8 y)
#define NBLK_B 64     // 4 vol x 2 z-groups(32 z) x  8 y-chunks(8 y)
#define NBLK_TOTAL (NBLK_A + NBLK_B + 1)

using f4 = __attribute__((ext_vector_type(4))) float;

__device__ __forceinline__ float fmax3(float a, float b, float c) {
    return fmaxf(a, fmaxf(b, c));
}

__device__ __forceinline__ f4 fmax3v(f4 a, f4 b, f4 c) {
    f4 r;
    r.x = fmax3(a.x, b.x, c.x); r.y = fmax3(a.y, b.y, c.y);
    r.z = fmax3(a.z, b.z, c.z); r.w = fmax3(a.w, b.w, c.w);
    return r;
}

__device__ __forceinline__ f4 selv(bool h, f4 a, f4 b) {  // h ? a : b
    f4 r;
    r.x = h ? a.x : b.x; r.y = h ? a.y : b.y;
    r.z = h ? a.z : b.z; r.w = h ? a.w : b.w;
    return r;
}

__device__ __forceinline__ f4 shflv(f4 v, int srcLane) {
    f4 r;
    r.x = __shfl(v.x, srcLane); r.y = __shfl(v.y, srcLane);
    r.z = __shfl(v.z, srcLane); r.w = __shfl(v.w, srcLane);
    return r;
}

// Emit one output quad. Max-mask computed first from logits; gt quad loaded
// ONLY if some element is a local max (exec-masked branch -> no request
// otherwise). x-halo via wave shuffle (xq in low lane bits; edges overridden).
template <int XQ>
__device__ __forceinline__ void emit_row(
    const f4 zw0, const f4 zw1, const f4 zw2, const f4 c, const float* gp,
    int xq, float& loss, float& wsum)
{
    f4 cz = fmax3v(zw0, zw1, zw2);                    // y-fold
    float lco = __shfl_up(cz.w, 1);   if (xq == 0)      lco = cz.x;
    float rco = __shfl_down(cz.x, 1); if (xq == XQ - 1) rco = cz.w;
    float ms[4] = {fmax3(lco, cz.x, cz.y), fmax3(cz.x, cz.y, cz.z),
                   fmax3(cz.y, cz.z, cz.w), fmax3(cz.z, cz.w, rco)};
    float cs[4] = {c.x, c.y, c.z, c.w};
    bool mk[4] = {ms[0] == cs[0], ms[1] == cs[1], ms[2] == cs[2], ms[3] == cs[3]};
    if (mk[0] | mk[1] | mk[2] | mk[3]) {
        f4 g = __builtin_nontemporal_load((const f4*)gp);
        float gs[4] = {g.x, g.y, g.z, g.w};
#pragma unroll
        for (int k = 0; k < 4; ++k) {
            if (mk[k] && gs[k] == -1.0f) {
                float e = __expf(cs[k]);                  // e^x
                float u = __builtin_amdgcn_rcpf(1.0f + e);
                float sc = e * u;                         // sigmoid(x)
                float wv = sc * sc;
                wsum += wv;
                loss += (-__logf(u)) * wv;                // softplus(x)
            }
        }
    }
}

// One thread: fixed (x-quad, z-pair). Marches y0-1..y0+8 (10 rows, clamped),
// emitting 8 y-rows at both z and z+1. The 6 planes needed by the lane and
// its partner (lane^PSH, z-pair +/-2) are split 3/3 and one row exchanged per
// step via shuffle. h=0: loads z-1,z,z+1 (recv=z+2); h=1: z,z+1,z+2 (recv=z-1).
// Exchanged planes are always interior (no clamp interaction). Boundary:
// index clamping duplicates an in-window value -> max unchanged.
template <int D, int LOG2D, int XQ, int PSH>
__device__ __forceinline__ void neg_march2(
    const float* __restrict__ logits, const float* __restrict__ gt,
    int vol, int z, int y0, int xq, int h, int lane,
    float& loss, float& wsum)
{
    const int x0 = xq << 2;
    const float* vb = logits + (vol << (3 * LOG2D));
    const int pa = h ? z : (z > 0 ? z - 1 : 0);
    const int pb = h ? z + 1 : z;
    const int pc = h ? (z + 2 < D ? z + 2 : D - 1) : z + 1;
    const float* P0 = vb + (pa << (2 * LOG2D));
    const float* P1 = vb + (pb << (2 * LOG2D));
    const float* P2 = vb + (pc << (2 * LOG2D));
    const float* g1 = gt + (vol << (3 * LOG2D)) + (z << (2 * LOG2D)) + x0;
    const float* g2 = g1 + (1 << (2 * LOG2D));
    const int partner = lane ^ PSH;

    f4 za[3], zb[3];   // rings: z-folded col max for output planes z / z+1
    f4 ca[2], cb[2];   // rings: center raw quads (planes z / z+1)

#pragma unroll
    for (int s = 0; s < 10; ++s) {
        int yy = y0 - 1 + s;
        yy = yy < 0 ? 0 : (yy > D - 1 ? D - 1 : yy);
        const int ro = (yy << LOG2D) + x0;
        f4 r0 = *(const f4*)(P0 + ro);
        f4 r1 = *(const f4*)(P1 + ro);
        f4 r2 = *(const f4*)(P2 + ro);
        f4 send = selv(h, r0, r2);
        f4 recv = shflv(send, partner);
        // ordered quartet of planes z-1, z, z+1, z+2
        f4 q0 = selv(h, recv, r0);
        f4 q1 = selv(h, r0, r1);
        f4 q2 = selv(h, r1, r2);
        f4 q3 = selv(h, r2, recv);
        za[s % 3] = fmax3v(q0, q1, q2);
        zb[s % 3] = fmax3v(q1, q2, q3);
        ca[s & 1] = q1;
        cb[s & 1] = q2;
        if (s >= 2) {
            const int yo = (y0 + s - 2) << LOG2D;
            emit_row<XQ>(za[0], za[1], za[2], ca[(s - 1) & 1], g1 + yo,
                         xq, loss, wsum);
            emit_row<XQ>(zb[0], zb[1], zb[2], cb[(s - 1) & 1], g2 + yo,
                         xq, loss, wsum);
        }
    }
}

__global__ __launch_bounds__(256, 4) void fused_kernel(
    const float* __restrict__ la, const float* __restrict__ lb,
    const float* __restrict__ ga, const float* __restrict__ gb,
    const int* __restrict__ conn_a, const int* __restrict__ conn_b,
    const int* __restrict__ coord_a, const int* __restrict__ coord_b,
    float* __restrict__ ws, float* __restrict__ out)
{
    __shared__ float sred[8];
    __shared__ float w1s[128];
    __shared__ float tgf[128];
    const int bid = blockIdx.x;
    const int t = threadIdx.x;
    const int lane = t & 63;
    float loss = 0.0f, wsum = 0.0f;
    int accIdx = -1;

    if (bid < NBLK_A) {
        // level a: D=128. xq = t&31, z-pair = t>>5 (block: 16 z x 8 y).
        // XCD swizzle: xcd = bid&7 owns z-group c (16 z) for all 4 vols.
        accIdx = 0;
        const int c = bid & 7;
        const int g = bid >> 3;        // 0..63
        const int yc = g & 15;
        const int vol = g >> 4;
        neg_march2<128, 7, 32, 32>(la, ga, vol, c * 16 + (t >> 5) * 2, yc * 8,
                                   t & 31, (t >> 5) & 1, lane, loss, wsum);
    } else if (bid < NBLK_A + NBLK_B) {
        // level b: D=64. xq = t&15, z-pair = t>>4 (block: 32 z x 8 y).
        accIdx = 2;
        const int b2 = bid - NBLK_A;
        const int c = b2 & 7;
        const int yc = b2 >> 3;
        const int vol = c >> 1;
        const int zg = c & 1;
        neg_march2<64, 6, 16, 16>(lb, gb, vol, zg * 32 + (t >> 4) * 2, yc * 8,
                                  t & 15, (t >> 4) & 1, lane, loss, wsum);
    } else {
        // pos block: both levels, 128 active threads
        for (int level = 0; level < 2; ++level) {
            const float* logits = level ? lb : la;
            const int* conn = level ? conn_b : conn_a;
            const int* coord = level ? coord_b : coord_a;
            const int D = level ? 64 : 128;
            float li = 0.0f, ci = 0.0f;
            if (t < 128) {
                const int* c4 = coord + t * 4;
                int a = c4[0], zz = c4[1], yy = c4[2], xx = c4[3];
                bool valid = a > -1;
                int aa = valid ? a : 0, z2 = valid ? zz : 0,
                    y2 = valid ? yy : 0, x2 = valid ? xx : 0;
                int b = t >> 6;
                int off = (((b * 2 + aa) * D + z2) * D + y2) * D + x2;
                float lp = logits[off];
                int tag = conn[off];
                float s = 1.0f / (1.0f + expf(lp));   // 1 - sigmoid(lp)
                float w1 = s * s;
                float vf = valid ? 1.0f : 0.0f;
                float sp = fmaxf(-lp, 0.0f) + log1pf(expf(-fabsf(lp)));  // softplus(-lp)
                li = sp * w1 * vf;
                ci = w1 * vf;
                w1s[t] = w1;
                tgf[t] = (float)(valid ? tag : -1);
            }
            for (int o = 32; o; o >>= 1) {
                li += __shfl_down(li, o);
                ci += __shfl_down(ci, o);
            }
            if ((t & 63) == 0) { sred[t >> 6] = li; sred[4 + (t >> 6)] = ci; }
            __syncthreads();
            if (t == 0) {
                atomicAdd(ws + 4 + 2 * level, sred[0] + sred[1] + sred[2] + sred[3]);
                atomicAdd(ws + 5 + 2 * level, sred[4] + sred[5] + sred[6] + sred[7]);
            }
            if (t < 16) {
                int bb = t >> 3, tg = t & 7;
                float mn = INFINITY;
                for (int i = 0; i < 64; ++i) {
                    int j = bb * 64 + i;
                    if (tgf[j] == (float)tg) mn = fminf(mn, w1s[j]);
                }
                out[6 + level * 16 + bb * 8 + tg] = isinf(mn) ? -1.0f : mn;
            }
            __syncthreads();
        }
    }

    if (accIdx >= 0) {
        for (int o = 32; o; o >>= 1) {
            loss += __shfl_down(loss, o);
            wsum += __shfl_down(wsum, o);
        }
        if ((t & 63) == 0) { sred[t >> 6] = loss; sred[4 + (t >> 6)] = wsum; }
        __syncthreads();
        if (t == 0) {
            float L = sred[0] + sred[1] + sred[2] + sred[3];
            float W = sred[4] + sred[5] + sred[6] + sred[7];
            if (L != 0.0f || W != 0.0f) {
                atomicAdd(ws + accIdx, L);
                atomicAdd(ws + accIdx + 1, W);
            }
        }
    }

    // last-block finalize
    if (t == 0) {
        __threadfence();
        unsigned int old = atomicAdd((unsigned int*)(ws + 8), 1u);
        if (old == NBLK_TOTAL - 1) {
            float s0 = atomicAdd(ws + 0, 0.0f);
            float s1 = atomicAdd(ws + 1, 0.0f);
            float s2 = atomicAdd(ws + 2, 0.0f);
            float s3 = atomicAdd(ws + 3, 0.0f);
            float s4 = atomicAdd(ws + 4, 0.0f);
            float s5 = atomicAdd(ws + 5, 0.0f);
            float s6 = atomicAdd(ws + 6, 0.0f);
            float s7 = atomicAdd(ws + 7, 0.0f);
            out[0] = s4 * 2.0f + s6;   // cls_loss_pos (POS_FACTOR {2,1})
            out[1] = s0 * 2.0f + s2;   // cls_loss_neg (NEG_FACTOR {2,1})
            out[2] = s5 + s7;          // count_pos
            out[3] = s1 + s3;          // count_neg
            out[4] = s5 * 2.0f + s7;   // wsum_pos (anchor factor == 1)
            out[5] = s1 * 2.0f + s3;   // wsum_neg
        }
    }
}

extern "C" void kernel_launch(void* const* d_in, const int* in_sizes, int n_in,
                              void* d_out, int out_size, void* d_ws, size_t ws_size,
                              hipStream_t stream) {
    const float* logits_a = (const float*)d_in[0];
    const float* logits_b = (const float*)d_in[1];
    const float* prob_a   = (const float*)d_in[2];
    const float* prob_b   = (const float*)d_in[3];
    const int*   conn_a   = (const int*)d_in[4];
    const int*   conn_b   = (const int*)d_in[5];
    const int*   coord_a  = (const int*)d_in[6];
    const int*   coord_b  = (const int*)d_in[7];
    float* out = (float*)d_out;
    float* ws  = (float*)d_ws;

    hipMemsetAsync(ws, 0, 12 * sizeof(float), stream);
    fused_kernel<<<NBLK_TOTAL, 256, 0, stream>>>(
        logits_a, logits_b, prob_a, prob_b,
        conn_a, conn_b, coord_a, coord_b, ws, out);
}

// Round 12
// 164.507 us; speedup vs baseline: 1.0083x; 1.0083x over previous
//
#include <hip/hip_runtime.h>
#include <math.h>

// Focal_loss2 — single fused dispatch. R12 = R10 (the 48 µs kernel: rolling
// y-march, XCD swizzle, ringed gt loads) with z-QUAD per thread: 4 output
// planes from 6 loaded planes, cutting requests/elem 0.875 -> 0.719.
// Law (R4/R7/R10, independent-load structures only): dur ~= 55 µs x req/elem.
// R11's regression (shuffle plane-exchange + predicated gt, 72 µs) showed
// added dependencies break the law — this round adds none.
//   neg: w = sigmoid(x)^2 * (gt==-1) * (x is 3x3x3 local max); loss += softplus(x)*w
//        local-max test in logit space (monotone sigmoid; validated R3-R11, absmax 0.0)
//   pos: 64 coords/batch/level gather; w1=(1-sigmoid)^2; per-(b,tag) min of w1
// ws (floats): [0]=lossneg_a [1]=wneg_a [2]=lossneg_b [3]=wneg_b
//              [4]=losspos_a [5]=cntpos_a [6]=losspos_b [7]=cntpos_b [8]=block counter
// out: [0]=cls_loss_pos [1]=cls_loss_neg [2]=count_pos [3]=count_neg
//      [4]=wsum_pos [5]=wsum_neg [6..37]=pred_prob_min[2][B=2][T=8]

#define NBLK_A 512    // 4 vol x 8 z-groups(16 z) x 16 y-chunks(8 y); block 16z x 8y
#define NBLK_B 64     // 4 vol x 2 z-groups(32 z) x  8 y-chunks(8 y); block 32z x 8y
#define NBLK_TOTAL (NBLK_A + NBLK_B + 1)

using f4 = __attribute__((ext_vector_type(4))) float;

__device__ __forceinline__ float fmax3(float a, float b, float c) {
    return fmaxf(a, fmaxf(b, c));
}

__device__ __forceinline__ f4 fmax3v(f4 a, f4 b, f4 c) {
    f4 r;
    r.x = fmax3(a.x, b.x, c.x); r.y = fmax3(a.y, b.y, c.y);
    r.z = fmax3(a.z, b.z, c.z); r.w = fmax3(a.w, b.w, c.w);
    return r;
}

// Emit one output quad (R10-identical). x-halo via wave shuffle (xq in the
// low lane bits; group edges overridden by the clamp rule).
template <int XQ>
__device__ __forceinline__ void emit_row(
    const f4 zw0, const f4 zw1, const f4 zw2, const f4 c, const f4 g,
    int xq, float& loss, float& wsum)
{
    f4 cz = fmax3v(zw0, zw1, zw2);                    // y-fold
    float lco = __shfl_up(cz.w, 1);   if (xq == 0)      lco = cz.x;
    float rco = __shfl_down(cz.x, 1); if (xq == XQ - 1) rco = cz.w;
    float ms[4] = {fmax3(lco, cz.x, cz.y), fmax3(cz.x, cz.y, cz.z),
                   fmax3(cz.y, cz.z, cz.w), fmax3(cz.z, cz.w, rco)};
    float cs[4] = {c.x, c.y, c.z, c.w};
    float gs[4] = {g.x, g.y, g.z, g.w};
#pragma unroll
    for (int k = 0; k < 4; ++k) {
        if (gs[k] == -1.0f && ms[k] == cs[k]) {
            float e = __expf(cs[k]);                  // e^x
            float u = __builtin_amdgcn_rcpf(1.0f + e);
            float sc = e * u;                         // sigmoid(x)
            float wv = sc * sc;
            wsum += wv;
            loss += (-__logf(u)) * wv;                // softplus(x)
        }
    }
}

// One thread: fixed (x-quad, z-QUAD). Marches y0-1..y0+8 (10 rows, clamped),
// emitting 8 y-rows at z..z+3 from 6 planes z-1..z+4. All loads independent
// (6 logit rows + 4 ringed gt rows per step). Boundary: index clamping
// duplicates an in-window value -> max unchanged.
template <int D, int LOG2D, int XQ>
__device__ __forceinline__ void neg_march4(
    const float* __restrict__ logits, const float* __restrict__ gt,
    int vol, int z, int y0, int xq, float& loss, float& wsum)
{
    const int x0 = xq << 2;
    const float* vb = logits + (vol << (3 * LOG2D));
    const int pm = z > 0 ? z - 1 : 0;
    const int pq = z + 4 < D ? z + 4 : D - 1;
    const float* P0 = vb + (pm << (2 * LOG2D));
    const float* P1 = vb + (z << (2 * LOG2D));
    const float* P2 = vb + ((z + 1) << (2 * LOG2D));
    const float* P3 = vb + ((z + 2) << (2 * LOG2D));
    const float* P4 = vb + ((z + 3) << (2 * LOG2D));
    const float* P5 = vb + (pq << (2 * LOG2D));
    const float* gbase = gt + (vol << (3 * LOG2D)) + (z << (2 * LOG2D)) + x0;

    f4 zf[4][3];   // rings: z-folded column max per output plane
    f4 cc[4][2];   // rings: center raw quads per output plane
    f4 gg[4][2];   // rings: gt quads per output plane (loaded 1 step ahead)

#pragma unroll
    for (int s = 0; s < 10; ++s) {
        int yy = y0 - 1 + s;
        yy = yy < 0 ? 0 : (yy > D - 1 ? D - 1 : yy);
        const int ro = (yy << LOG2D) + x0;
        f4 r0 = *(const f4*)(P0 + ro);
        f4 r1 = *(const f4*)(P1 + ro);
        f4 r2 = *(const f4*)(P2 + ro);
        f4 r3 = *(const f4*)(P3 + ro);
        f4 r4 = *(const f4*)(P4 + ro);
        f4 r5 = *(const f4*)(P5 + ro);
        if (s >= 1 && s <= 8) {       // gt rows: single-use stream
            const int go = (y0 + s - 1) << LOG2D;
#pragma unroll
            for (int j = 0; j < 4; ++j)
                gg[j][s & 1] = __builtin_nontemporal_load(
                    (const f4*)(gbase + (j << (2 * LOG2D)) + go));
        }
        zf[0][s % 3] = fmax3v(r0, r1, r2);
        zf[1][s % 3] = fmax3v(r1, r2, r3);
        zf[2][s % 3] = fmax3v(r2, r3, r4);
        zf[3][s % 3] = fmax3v(r3, r4, r5);
        cc[0][s & 1] = r1; cc[1][s & 1] = r2;
        cc[2][s & 1] = r3; cc[3][s & 1] = r4;
        if (s >= 2) {
#pragma unroll
            for (int j = 0; j < 4; ++j)
                emit_row<XQ>(zf[j][0], zf[j][1], zf[j][2],
                             cc[j][(s - 1) & 1], gg[j][(s - 1) & 1],
                             xq, loss, wsum);
        }
    }
}

__global__ __launch_bounds__(128, 3) void fused_kernel(
    const float* __restrict__ la, const float* __restrict__ lb,
    const float* __restrict__ ga, const float* __restrict__ gb,
    const int* __restrict__ conn_a, const int* __restrict__ conn_b,
    const int* __restrict__ coord_a, const int* __restrict__ coord_b,
    float* __restrict__ ws, float* __restrict__ out)
{
    __shared__ float sred[8];
    __shared__ float w1s[128];
    __shared__ float tgf[128];
    const int bid = blockIdx.x;
    const int t = threadIdx.x;   // block = 128 threads (2 waves)
    float loss = 0.0f, wsum = 0.0f;
    int accIdx = -1;

    if (bid < NBLK_A) {
        // level a: D=128. xq = t&31, z-quad = t>>5 (0..3): block 16 z x 8 y.
        // XCD swizzle: c = bid&7; 32 (vol x 16z-group) units, 4 per XCD.
        accIdx = 0;
        const int c = bid & 7;
        const int g = bid >> 3;        // 0..63
        const int yc = g & 15;         // y fastest
        const int j = g >> 4;          // 0..3
        const int unit = c * 4 + j;    // 0..31
        const int vol = unit >> 3;
        const int zg = unit & 7;
        neg_march4<128, 7, 32>(la, ga, vol, zg * 16 + (t >> 5) * 4, yc * 8,
                               t & 31, loss, wsum);
    } else if (bid < NBLK_A + NBLK_B) {
        // level b: D=64. xq = t&15, z-quad = t>>4 (0..7): block 32 z x 8 y.
        accIdx = 2;
        const int b2 = bid - NBLK_A;
        const int c = b2 & 7;
        const int vol = c >> 1;
        const int zg = c & 1;
        const int yc = b2 >> 3;        // 0..7
        neg_march4<64, 6, 16>(lb, gb, vol, zg * 32 + (t >> 4) * 4, yc * 8,
                              t & 15, loss, wsum);
    } else {
        // pos block: both levels, 128 threads
        for (int level = 0; level < 2; ++level) {
            const float* logits = level ? lb : la;
            const int* conn = level ? conn_b : conn_a;
            const int* coord = level ? coord_b : coord_a;
            const int D = level ? 64 : 128;
            const int* c4 = coord + t * 4;
            int a = c4[0], zz = c4[1], yy = c4[2], xx = c4[3];
            bool valid = a > -1;
            int aa = valid ? a : 0, z2 = valid ? zz : 0,
                y2 = valid ? yy : 0, x2 = valid ? xx : 0;
            int b = t >> 6;
            int off = (((b * 2 + aa) * D + z2) * D + y2) * D + x2;
            float lp = logits[off];
            int tag = conn[off];
            float s = 1.0f / (1.0f + expf(lp));   // 1 - sigmoid(lp)
            float w1 = s * s;
            float vf = valid ? 1.0f : 0.0f;
            float sp = fmaxf(-lp, 0.0f) + log1pf(expf(-fabsf(lp)));  // softplus(-lp)
            float li = sp * w1 * vf;
            float ci = w1 * vf;
            w1s[t] = w1;
            tgf[t] = (float)(valid ? tag : -1);
            for (int o = 32; o; o >>= 1) {
                li += __shfl_down(li, o);
                ci += __shfl_down(ci, o);
            }
            if ((t & 63) == 0) { sred[t >> 6] = li; sred[4 + (t >> 6)] = ci; }
            __syncthreads();
            if (t == 0) {
                atomicAdd(ws + 4 + 2 * level, sred[0] + sred[1]);
                atomicAdd(ws + 5 + 2 * level, sred[4] + sred[5]);
            }
            if (t < 16) {
                int bb = t >> 3, tg = t & 7;
                float mn = INFINITY;
                for (int i = 0; i < 64; ++i) {
                    int j = bb * 64 + i;
                    if (tgf[j] == (float)tg) mn = fminf(mn, w1s[j]);
                }
                out[6 + level * 16 + bb * 8 + tg] = isinf(mn) ? -1.0f : mn;
            }
            __syncthreads();
        }
    }

    if (accIdx >= 0) {
        for (int o = 32; o; o >>= 1) {
            loss += __shfl_down(loss, o);
            wsum += __shfl_down(wsum, o);
        }
        if ((t & 63) == 0) { sred[t >> 6] = loss; sred[4 + (t >> 6)] = wsum; }
        __syncthreads();
        if (t == 0) {
            float L = sred[0] + sred[1];
            float W = sred[4] + sred[5];
            if (L != 0.0f || W != 0.0f) {
                atomicAdd(ws + accIdx, L);
                atomicAdd(ws + accIdx + 1, W);
            }
        }
    }

    // last-block finalize
    if (t == 0) {
        __threadfence();
        unsigned int old = atomicAdd((unsigned int*)(ws + 8), 1u);
        if (old == NBLK_TOTAL - 1) {
            float s0 = atomicAdd(ws + 0, 0.0f);
            float s1 = atomicAdd(ws + 1, 0.0f);
            float s2 = atomicAdd(ws + 2, 0.0f);
            float s3 = atomicAdd(ws + 3, 0.0f);
            float s4 = atomicAdd(ws + 4, 0.0f);
            float s5 = atomicAdd(ws + 5, 0.0f);
            float s6 = atomicAdd(ws + 6, 0.0f);
            float s7 = atomicAdd(ws + 7, 0.0f);
            out[0] = s4 * 2.0f + s6;   // cls_loss_pos (POS_FACTOR {2,1})
            out[1] = s0 * 2.0f + s2;   // cls_loss_neg (NEG_FACTOR {2,1})
            out[2] = s5 + s7;          // count_pos
            out[3] = s1 + s3;          // count_neg
            out[4] = s5 * 2.0f + s7;   // wsum_pos (anchor factor == 1)
            out[5] = s1 * 2.0f + s3;   // wsum_neg
        }
    }
}

extern "C" void kernel_launch(void* const* d_in, const int* in_sizes, int n_in,
                              void* d_out, int out_size, void* d_ws, size_t ws_size,
                              hipStream_t stream) {
    const float* logits_a = (const float*)d_in[0];
    const float* logits_b = (const float*)d_in[1];
    const float* prob_a   = (const float*)d_in[2];
    const float* prob_b   = (const float*)d_in[3];
    const int*   conn_a   = (const int*)d_in[4];
    const int*   conn_b   = (const int*)d_in[5];
    const int*   coord_a  = (const int*)d_in[6];
    const int*   coord_b  = (const int*)d_in[7];
    float* out = (float*)d_out;
    float* ws  = (float*)d_ws;

    hipMemsetAsync(ws, 0, 12 * sizeof(float), stream);
    fused_kernel<<<NBLK_TOTAL, 128, 0, stream>>>(
        logits_a, logits_b, prob_a, prob_b,
        conn_a, conn_b, coord_a, coord_b, ws, out);
}

// Round 13
// 162.205 us; speedup vs baseline: 1.0226x; 1.0142x over previous
//
#include <hip/hip_runtime.h>
#include <math.h>

// Focal_loss2 — single fused dispatch. R13 = R10 (best: 48 µs kernel / 163 µs
// total; z-paired rolling y-march, XCD swizzle, ringed NT gt loads) with ONE
// delta: logit loads are also NON-TEMPORAL. Theory: the structure-invariant
// ~48-70 µs wall (VALU~2µs, HBM~7µs, L2BW~4µs, issue~3µs all idle) is L1
// set-conflict serialization — the 64KB z-plane stride aliases all plane
// streams onto the same L1 sets and line-fill conflicts serialize the memory
// pipe. NT loads skip L1 allocation -> no set-fill conflicts. Discriminating
// test: big win if theory right, neutral if the L2 path is the wall.
//   neg: w = sigmoid(x)^2 * (gt==-1) * (x is 3x3x3 local max); loss += softplus(x)*w
//        local-max test in logit space (monotone sigmoid; validated R3-R12, absmax 0.0)
//   pos: 64 coords/batch/level gather; w1=(1-sigmoid)^2; per-(b,tag) min of w1
// ws (floats): [0]=lossneg_a [1]=wneg_a [2]=lossneg_b [3]=wneg_b
//              [4]=losspos_a [5]=cntpos_a [6]=losspos_b [7]=cntpos_b [8]=block counter
// out: [0]=cls_loss_pos [1]=cls_loss_neg [2]=count_pos [3]=count_neg
//      [4]=wsum_pos [5]=wsum_neg [6..37]=pred_prob_min[2][B=2][T=8]

#define NBLK_A 512    // 4 vol x 8 z-groups(16 z) x 16 y-chunks(8 y)
#define NBLK_B 64     // 4 vol x 2 z-groups(32 z) x  8 y-chunks(8 y)
#define NBLK_TOTAL (NBLK_A + NBLK_B + 1)

using f4 = __attribute__((ext_vector_type(4))) float;

__device__ __forceinline__ float fmax3(float a, float b, float c) {
    return fmaxf(a, fmaxf(b, c));
}

__device__ __forceinline__ f4 fmax3v(f4 a, f4 b, f4 c) {
    f4 r;
    r.x = fmax3(a.x, b.x, c.x); r.y = fmax3(a.y, b.y, c.y);
    r.z = fmax3(a.z, b.z, c.z); r.w = fmax3(a.w, b.w, c.w);
    return r;
}

// Emit one output quad. x-halo via wave shuffle (xq in low lane bits; group
// edges overridden by the clamp rule).
template <int XQ>
__device__ __forceinline__ void emit_row(
    const f4 zw0, const f4 zw1, const f4 zw2, const f4 c, const f4 g,
    int xq, float& loss, float& wsum)
{
    f4 cz = fmax3v(zw0, zw1, zw2);                    // y-fold
    float lco = __shfl_up(cz.w, 1);   if (xq == 0)      lco = cz.x;
    float rco = __shfl_down(cz.x, 1); if (xq == XQ - 1) rco = cz.w;
    float ms[4] = {fmax3(lco, cz.x, cz.y), fmax3(cz.x, cz.y, cz.z),
                   fmax3(cz.y, cz.z, cz.w), fmax3(cz.z, cz.w, rco)};
    float cs[4] = {c.x, c.y, c.z, c.w};
    float gs[4] = {g.x, g.y, g.z, g.w};
#pragma unroll
    for (int k = 0; k < 4; ++k) {
        if (gs[k] == -1.0f && ms[k] == cs[k]) {
            float e = __expf(cs[k]);                  // e^x
            float u = __builtin_amdgcn_rcpf(1.0f + e);
            float sc = e * u;                         // sigmoid(x)
            float wv = sc * sc;
            wsum += wv;
            loss += (-__logf(u)) * wv;                // softplus(x)
        }
    }
}

// One thread: fixed (x-quad, z-pair). Marches y0-1..y0+8 (10 rows, clamped),
// emitting 8 y-rows at BOTH z and z+1 from 4 planes z-1..z+2 (z-pairing).
// All loads non-temporal (bypass the set-aliased L1). Boundary: index
// clamping duplicates an in-window value -> max unchanged.
template <int D, int LOG2D, int XQ>
__device__ __forceinline__ void neg_march2(
    const float* __restrict__ logits, const float* __restrict__ gt,
    int vol, int z, int y0, int xq, float& loss, float& wsum)
{
    const int x0 = xq << 2;
    const float* vb = logits + (vol << (3 * LOG2D));
    const int zm = z > 0 ? z - 1 : 0;              // z+1 <= D-1 by construction
    const int zq = z + 2 < D ? z + 2 : D - 1;
    const float* p0 = vb + (zm << (2 * LOG2D));
    const float* p1 = vb + (z << (2 * LOG2D));
    const float* p2 = vb + ((z + 1) << (2 * LOG2D));
    const float* p3 = vb + (zq << (2 * LOG2D));
    const float* g1 = gt + (vol << (3 * LOG2D)) + (z << (2 * LOG2D));
    const float* g2 = g1 + (1 << (2 * LOG2D));

    f4 za[3], zb[3];   // rings: z-folded col max for output z / z+1
    f4 ca[2], cb[2];   // rings: center raw quads (plane z / z+1)
    f4 ga[2], gb[2];   // rings: gt quads

#pragma unroll
    for (int s = 0; s < 10; ++s) {
        int yy = y0 - 1 + s;
        yy = yy < 0 ? 0 : (yy > D - 1 ? D - 1 : yy);
        const int ro = (yy << LOG2D) + x0;
        f4 r0 = __builtin_nontemporal_load((const f4*)(p0 + ro));
        f4 r1 = __builtin_nontemporal_load((const f4*)(p1 + ro));
        f4 r2 = __builtin_nontemporal_load((const f4*)(p2 + ro));
        f4 r3 = __builtin_nontemporal_load((const f4*)(p3 + ro));
        if (s >= 1 && s <= 8) {       // gt rows: single-use stream
            ga[s & 1] = __builtin_nontemporal_load((const f4*)(g1 + ro));
            gb[s & 1] = __builtin_nontemporal_load((const f4*)(g2 + ro));
        }
        za[s % 3] = fmax3v(r0, r1, r2);
        zb[s % 3] = fmax3v(r1, r2, r3);
        ca[s & 1] = r1;
        cb[s & 1] = r2;
        if (s >= 2) {
            emit_row<XQ>(za[0], za[1], za[2], ca[(s - 1) & 1], ga[(s - 1) & 1],
                         xq, loss, wsum);
            emit_row<XQ>(zb[0], zb[1], zb[2], cb[(s - 1) & 1], gb[(s - 1) & 1],
                         xq, loss, wsum);
        }
    }
}

__global__ __launch_bounds__(256, 4) void fused_kernel(
    const float* __restrict__ la, const float* __restrict__ lb,
    const float* __restrict__ ga, const float* __restrict__ gb,
    const int* __restrict__ conn_a, const int* __restrict__ conn_b,
    const int* __restrict__ coord_a, const int* __restrict__ coord_b,
    float* __restrict__ ws, float* __restrict__ out)
{
    __shared__ float sred[8];
    __shared__ float w1s[128];
    __shared__ float tgf[128];
    const int bid = blockIdx.x;
    const int t = threadIdx.x;
    float loss = 0.0f, wsum = 0.0f;
    int accIdx = -1;

    if (bid < NBLK_A) {
        // level a: D=128. xq = t&31, z-pair = t>>5 (block: 16 z x 8 y).
        // XCD swizzle: xcd = bid&7 owns z-group c (16 z) for all 4 vols.
        accIdx = 0;
        const int c = bid & 7;
        const int g = bid >> 3;        // 0..63
        const int yc = g & 15;         // y fastest
        const int vol = g >> 4;
        neg_march2<128, 7, 32>(la, ga, vol, c * 16 + (t >> 5) * 2, yc * 8,
                               t & 31, loss, wsum);
    } else if (bid < NBLK_A + NBLK_B) {
        // level b: D=64. xq = t&15, z-pair = t>>4 (block: 32 z x 8 y).
        accIdx = 2;
        const int b2 = bid - NBLK_A;
        const int c = b2 & 7;
        const int yc = b2 >> 3;
        const int vol = c >> 1;
        const int zg = c & 1;
        neg_march2<64, 6, 16>(lb, gb, vol, zg * 32 + (t >> 4) * 2, yc * 8,
                              t & 15, loss, wsum);
    } else {
        // pos block: both levels, 128 active threads
        for (int level = 0; level < 2; ++level) {
            const float* logits = level ? lb : la;
            const int* conn = level ? conn_b : conn_a;
            const int* coord = level ? coord_b : coord_a;
            const int D = level ? 64 : 128;
            float li = 0.0f, ci = 0.0f;
            if (t < 128) {
                const int* c4 = coord + t * 4;
                int a = c4[0], zz = c4[1], yy = c4[2], xx = c4[3];
                bool valid = a > -1;
                int aa = valid ? a : 0, z2 = valid ? zz : 0,
                    y2 = valid ? yy : 0, x2 = valid ? xx : 0;
                int b = t >> 6;
                int off = (((b * 2 + aa) * D + z2) * D + y2) * D + x2;
                float lp = logits[off];
                int tag = conn[off];
                float s = 1.0f / (1.0f + expf(lp));   // 1 - sigmoid(lp)
                float w1 = s * s;
                float vf = valid ? 1.0f : 0.0f;
                float sp = fmaxf(-lp, 0.0f) + log1pf(expf(-fabsf(lp)));  // softplus(-lp)
                li = sp * w1 * vf;
                ci = w1 * vf;
                w1s[t] = w1;
                tgf[t] = (float)(valid ? tag : -1);
            }
            for (int o = 32; o; o >>= 1) {
                li += __shfl_down(li, o);
                ci += __shfl_down(ci, o);
            }
            if ((t & 63) == 0) { sred[t >> 6] = li; sred[4 + (t >> 6)] = ci; }
            __syncthreads();
            if (t == 0) {
                atomicAdd(ws + 4 + 2 * level, sred[0] + sred[1] + sred[2] + sred[3]);
                atomicAdd(ws + 5 + 2 * level, sred[4] + sred[5] + sred[6] + sred[7]);
            }
            if (t < 16) {
                int bb = t >> 3, tg = t & 7;
                float mn = INFINITY;
                for (int i = 0; i < 64; ++i) {
                    int j = bb * 64 + i;
                    if (tgf[j] == (float)tg) mn = fminf(mn, w1s[j]);
                }
                out[6 + level * 16 + bb * 8 + tg] = isinf(mn) ? -1.0f : mn;
            }
            __syncthreads();
        }
    }

    if (accIdx >= 0) {
        for (int o = 32; o; o >>= 1) {
            loss += __shfl_down(loss, o);
            wsum += __shfl_down(wsum, o);
        }
        if ((t & 63) == 0) { sred[t >> 6] = loss; sred[4 + (t >> 6)] = wsum; }
        __syncthreads();
        if (t == 0) {
            float L = sred[0] + sred[1] + sred[2] + sred[3];
            float W = sred[4] + sred[5] + sred[6] + sred[7];
            if (L != 0.0f || W != 0.0f) {
                atomicAdd(ws + accIdx, L);
                atomicAdd(ws + accIdx + 1, W);
            }
        }
    }

    // last-block finalize
    if (t == 0) {
        __threadfence();
        unsigned int old = atomicAdd((unsigned int*)(ws + 8), 1u);
        if (old == NBLK_TOTAL - 1) {
            float s0 = atomicAdd(ws + 0, 0.0f);
            float s1 = atomicAdd(ws + 1, 0.0f);
            float s2 = atomicAdd(ws + 2, 0.0f);
            float s3 = atomicAdd(ws + 3, 0.0f);
            float s4 = atomicAdd(ws + 4, 0.0f);
            float s5 = atomicAdd(ws + 5, 0.0f);
            float s6 = atomicAdd(ws + 6, 0.0f);
            float s7 = atomicAdd(ws + 7, 0.0f);
            out[0] = s4 * 2.0f + s6;   // cls_loss_pos (POS_FACTOR {2,1})
            out[1] = s0 * 2.0f + s2;   // cls_loss_neg (NEG_FACTOR {2,1})
            out[2] = s5 + s7;          // count_pos
            out[3] = s1 + s3;          // count_neg
            out[4] = s5 * 2.0f + s7;   // wsum_pos (anchor factor == 1)
            out[5] = s1 * 2.0f + s3;   // wsum_neg
        }
    }
}

extern "C" void kernel_launch(void* const* d_in, const int* in_sizes, int n_in,
                              void* d_out, int out_size, void* d_ws, size_t ws_size,
                              hipStream_t stream) {
    const float* logits_a = (const float*)d_in[0];
    const float* logits_b = (const float*)d_in[1];
    const float* prob_a   = (const float*)d_in[2];
    const float* prob_b   = (const float*)d_in[3];
    const int*   conn_a   = (const int*)d_in[4];
    const int*   conn_b   = (const int*)d_in[5];
    const int*   coord_a  = (const int*)d_in[6];
    const int*   coord_b  = (const int*)d_in[7];
    float* out = (float*)d_out;
    float* ws  = (float*)d_ws;

    hipMemsetAsync(ws, 0, 12 * sizeof(float), stream);
    fused_kernel<<<NBLK_TOTAL, 256, 0, stream>>>(
        logits_a, logits_b, prob_a, prob_b,
        conn_a, conn_b, coord_a, coord_b, ws, out);
}